// Round 9
// baseline (491.005 us; speedup 1.0000x reference)
//
#include <hip/hip_runtime.h>
#include <cstdio>

// B=32, Cin=128, S=8192, H=4, Hc=32, M=64, Cout=128
#define S_LEN 8192
#define NM 64

typedef short s8v __attribute__((ext_vector_type(8)));   // 8 bf16
typedef float f4  __attribute__((ext_vector_type(4)));
typedef _Float16 h8 __attribute__((ext_vector_type(8))); // 8 fp16 (MFMA f16 frag)
typedef _Float16 h4v __attribute__((ext_vector_type(4)));

static __device__ inline unsigned short f2bf(float f) {  // RNE fp32->bf16
    unsigned int u = __builtin_bit_cast(unsigned int, f);
    u = (u + 0x7FFFu + ((u >> 16) & 1u)) >> 16;
    return (unsigned short)u;
}
static __device__ inline float bf2f(unsigned short h) {
    unsigned int u = ((unsigned int)h) << 16;
    return __builtin_bit_cast(float, u);
}

// K3-side swizzle: [128 r][32 k] tile, XOR k-bits 3..4 with (r>>1)&3
#define SW32(r, k) (((r) * 32) + ((k) ^ ((((r) >> 1) & 3) << 3)))

static __device__ __forceinline__ void glds16(const void* g, void* l) {
    __builtin_amdgcn_global_load_lds(
        (const __attribute__((address_space(1))) unsigned int*)g,
        (__attribute__((address_space(3))) unsigned int*)l, 16, 0, 0);
}

// ---------------- master trig table: tab[p] = cos(2*pi*p/8192) ----------------
__global__ __launch_bounds__(256) void gen_master(float* __restrict__ tab) {
    int p = blockIdx.x * 256 + threadIdx.x;
    tab[p] = cosf((float)p * (6.28318530717958647692f / (float)S_LEN));
}

// T1 image (K3's B^T): (s,k) k=2m|2m+1; img[(sb*4+kc)*4096 + SW32(s&127,k&31)]
// -sin(theta_p) == cos(theta_{p+2048})
__global__ __launch_bounds__(256) void gen_t1_img(const float* __restrict__ tab,
                                                  short* __restrict__ Th,
                                                  short* __restrict__ Tl) {
    int tid = blockIdx.x * 256 + threadIdx.x;     // 1M
    int tile = tid >> 12;
    int sb = tile >> 2, kc = tile & 3;
    int us = tid & 4095;
    int ls = us >> 5, kx = us & 31;
    int lk = kx ^ (((ls >> 1) & 3) << 3);
    int s = sb * 128 + ls;
    int k = kc * 32 + lk;
    int m = k >> 1;
    int p = (m * s + ((k & 1) << 11)) & (S_LEN - 1);
    float v = tab[p];                             // k odd -> -sin; k=1 gives 0 (Im(DC) dropped)
    unsigned short h = f2bf(v);
    Th[tid] = (short)h;
    Tl[tid] = (short)f2bf(v - bf2f(h));
}

// Bimg (K1's B, FRAGMENT order): [w32 256][cf 8][lane 64][8 fp16] = 2MB.
__global__ __launch_bounds__(256) void gen_b_img(const float* __restrict__ tab,
                                                 _Float16* __restrict__ Bimg) {
    int tid = blockIdx.x * 256 + threadIdx.x;     // 1M
    int e = tid & 7;
    int lane = (tid >> 3) & 63;
    int cf = (tid >> 9) & 7;
    int w32 = tid >> 12;
    int rl = lane & 15, kq = lane >> 4;
    int col = cf * 16 + rl;
    int m = col >> 1;
    int k = w32 * 32 + kq * 8 + e;
    int p = (m * k + ((col & 1) << 11)) & (S_LEN - 1);
    Bimg[tid] = (_Float16)tab[p];
}

// ---------------- K1 template: P[ks] = x * B1 (MODE NOA=true strips the A-path) ----------------
// 512 blocks x 512 thr. Block: 16 rows x K=4096 (32 steps of 128).
// A: fp32->fp16 hi/lo, LDS dbuf, prefetch dist 2. B: reg-prefetch dist 1 from L2 image.
#define LA(SC, AV)  { if constexpr (!NOA) {                                        \
        AV = *(const f4*)&x[xrow + (size_t)(SC) * 128]; } }

#define BLOAD(SC, BF) { _Pragma("unroll")                                          \
    for (int wd = 0; wd < 4; ++wd)                                                 \
        BF[wd] = *(const h8*)((const char*)Bimg + bbase + (size_t)((SC)*4+wd)*8192); }

#define CV(AV, NXT) { if constexpr (!NOA) { h4v hv, lv;                            \
        _Pragma("unroll")                                                          \
        for (int e = 0; e < 4; ++e) {                                              \
            float f = AV[e]; _Float16 hh = (_Float16)f;                            \
            hv[e] = hh; lv[e] = (_Float16)(f - (float)hh);                         \
        }                                                                          \
        *(h4v*)&abh[NXT][usA] = hv;                                                \
        *(h4v*)&abl[NXT][usA] = lv;                                                \
    } else {                                                                       \
        *(h4v*)&abh[NXT][usA] = chv;                                               \
        *(h4v*)&abl[NXT][usA] = clv; } }

#define MM(CUR, BF) { _Pragma("unroll")                                            \
    for (int wd = 0; wd < 4; ++wd) {                                               \
        const int sl = ((((wd << 2) + kq) ^ rl) & 15) << 3;                        \
        h8 Ah = *(const h8*)&abh[CUR][rl * 128 + sl];                              \
        h8 Al = *(const h8*)&abl[CUR][rl * 128 + sl];                              \
        acc = __builtin_amdgcn_mfma_f32_16x16x32_f16(Ah, BF[wd], acc, 0, 0, 0);    \
        acc = __builtin_amdgcn_mfma_f32_16x16x32_f16(Al, BF[wd], acc, 0, 0, 0); } }

#define BAR  __builtin_amdgcn_sched_barrier(0);                                    \
    asm volatile("s_waitcnt lgkmcnt(0)" ::: "memory");                             \
    __builtin_amdgcn_sched_barrier(0);                                             \
    __builtin_amdgcn_s_barrier();                                                  \
    __builtin_amdgcn_sched_barrier(0);

#define STEP(SC, LAC, AVL, AVC, NXT, CUR, BMM, BLD)                                \
    LA(LAC, AVL) BLOAD((SC)+1, BLD) CV(AVC, NXT) MM(CUR, BMM) BAR

template<int REPS, bool NOA>
__global__ __launch_bounds__(512, 4) void k1_t(const float* __restrict__ x,
        const _Float16* __restrict__ Bimg, float* __restrict__ P) {
    __shared__ _Float16 abh[2][16 * 128], abl[2][16 * 128];  // 16KB total
    const int t = threadIdx.x;
    const int lane = t & 63, w = t >> 6;
    const int rl = lane & 15, kq = lane >> 4;
    const int row0 = blockIdx.x * 16;
    const int ks = blockIdx.y;                    // 0..1
    const int rA = t >> 5, cA = (t & 31) * 4;
    const size_t xrow = (size_t)(row0 + rA) * S_LEN + (size_t)ks * (S_LEN / 2) + cA;
    const int usA = rA * 128 + ((((cA >> 3) ^ rA) & 15) << 3) + (cA & 7);
    const size_t bbase = (size_t)ks * 1048576 + (size_t)w * 1024 + (size_t)lane * 16;

    f4 acc = (f4){0.f, 0.f, 0.f, 0.f};
    f4 a0, a1, a2;
    h8 Be[4], Bo[4];
    h4v chv, clv;                                  // NOA stand-ins
    #pragma unroll
    for (int e = 0; e < 4; ++e) { chv[e] = (_Float16)0.5f; clv[e] = (_Float16)0.25f; }

    for (int rep = 0; rep < REPS; ++rep) {
        // prologue: chunks 0,1,2 in flight; B(0) in regs; stage chunk 0
        LA(0, a0) LA(1, a1) LA(2, a2)
        BLOAD(0, Be)
        CV(a0, 0)
        BAR
        for (int s = 0; s < 24; s += 6) {
            STEP(s + 0, s + 3, a0, a1, 1, 0, Be, Bo)
            STEP(s + 1, s + 4, a1, a2, 0, 1, Bo, Be)
            STEP(s + 2, s + 5, a2, a0, 1, 0, Be, Bo)
            STEP(s + 3, s + 6, a0, a1, 0, 1, Bo, Be)
            STEP(s + 4, s + 7, a1, a2, 1, 0, Be, Bo)
            STEP(s + 5, s + 8, a2, a0, 0, 1, Bo, Be)
        }
        STEP(24, 27, a0, a1, 1, 0, Be, Bo)
        STEP(25, 28, a1, a2, 0, 1, Bo, Be)
        STEP(26, 29, a2, a0, 1, 0, Be, Bo)
        STEP(27, 30, a0, a1, 0, 1, Bo, Be)
        STEP(28, 31, a1, a2, 1, 0, Be, Bo)
        STEP(29, 31, a2, a0, 0, 1, Bo, Be)   // dup-load chunk 31 (never consumed)
        // step 30 (even): BLOAD(31)->Bo, CV chunk31, MM Be
        BLOAD(31, Bo) CV(a1, 1) MM(0, Be) BAR
        // step 31: MFMA only
        MM(1, Bo);
    }

    float* Pks = P + (size_t)ks * 4096 * 128;
    #pragma unroll
    for (int r = 0; r < 4; ++r)
        Pks[(size_t)(row0 + kq * 4 + r) * 128 + w * 16 + rl] = acc[r];
}

// ---------------- V1: pure A-pattern stream (x and y alternating to defeat L3) ----------------
__global__ __launch_bounds__(512) void kstream(const float* __restrict__ a,
                                               const float* __restrict__ b,
                                               float* __restrict__ sink) {
    const int t = threadIdx.x;
    const int rA = t >> 5, cA = (t & 31) * 4;
    const int row0 = blockIdx.x * 16;
    const int ks = blockIdx.y;
    const size_t xrow = (size_t)(row0 + rA) * S_LEN + (size_t)ks * (S_LEN / 2) + cA;
    f4 s = (f4){0.f, 0.f, 0.f, 0.f};
    for (int rep = 0; rep < 5; ++rep) {
        #pragma unroll
        for (int sc = 0; sc < 32; ++sc)
            s += *(const f4*)&a[xrow + (size_t)sc * 128];
        #pragma unroll
        for (int sc = 0; sc < 32; ++sc)
            s += *(const f4*)&b[xrow + (size_t)sc * 128];
    }
    asm volatile("" :: "v"(s[0]), "v"(s[1]), "v"(s[2]), "v"(s[3]));
    if (s[0] == 1.2345e30f) sink[0] = s[1];       // never true; belt+braces vs DCE
}

// ---------------- ksum: X = P[0] + P[1] ----------------
__global__ __launch_bounds__(256) void ksum(const float* __restrict__ P,
                                            float* __restrict__ X) {
    int i = (blockIdx.x * 256 + threadIdx.x) * 4;
    f4 s = *(const f4*)&P[i];
    s += *(const f4*)&P[524288 + i];
    *(f4*)&X[i] = s;
}

// ---------------- K2: mode contraction -> C2 image (pre-swizzled bf16 hi/lo) ----------------
__global__ __launch_bounds__(256) void mode_contract(const float* __restrict__ X,
        const float* __restrict__ w_real, const float* __restrict__ w_imag,
        short* __restrict__ C2h, short* __restrict__ C2l) {
    __shared__ float xr[32][128], xi[32][128];
    __shared__ float wr[128][32], wi[128][32];
    const int m = blockIdx.x, h = blockIdx.y, t = threadIdx.x;
    #pragma unroll
    for (int it = 0; it < 16; ++it) {
        int li = t + it * 256;       // 0..4095
        int b = li >> 7, i = li & 127;
        const float2 v = *(const float2*)&X[(size_t)(b * 128 + i) * 128 + 2 * m];
        xr[b][i] = v.x; xi[b][i] = v.y;
        int i2 = li >> 5, o = li & 31;
        size_t off = ((size_t)((h * 128 + i2) * 32 + o)) * NM + m;
        wr[i2][o] = w_real[off];
        wi[i2][o] = w_imag[off];
    }
    __syncthreads();
    const int o = t & 31;
    const int b0 = (t >> 5) * 4;
    float re[4] = {0.f, 0.f, 0.f, 0.f}, im[4] = {0.f, 0.f, 0.f, 0.f};
    for (int i = 0; i < 128; ++i) {
        float wrv = wr[i][o], wiv = wi[i][o];
        #pragma unroll
        for (int j = 0; j < 4; ++j) {
            float a = xr[b0 + j][i], c = xi[b0 + j][i];
            re[j] += a * wrv - c * wiv;
            im[j] += a * wiv + c * wrv;
        }
    }
    const float alpha = (m == 0) ? (1.0f / (float)S_LEN) : (2.0f / (float)S_LEN);
    const int kc = m >> 4;
    const int lk = (2 * m) & 31;
    #pragma unroll
    for (int j = 0; j < 4; ++j) {
        int row = (b0 + j) * 128 + h * 32 + o;
        float vr = alpha * re[j], vi = alpha * im[j];
        unsigned short hr = f2bf(vr), hi_ = f2bf(vi);
        float lr = vr - bf2f(hr), li_ = vi - bf2f(hi_);
        int rb = row >> 7, lr_ = row & 127;
        size_t ui = ((size_t)(rb * 4 + kc) * 4096 + SW32(lr_, lk)) >> 1;   // uint index
        ((unsigned int*)C2h)[ui] = ((unsigned int)hi_ << 16) | hr;
        ((unsigned int*)C2l)[ui] = ((unsigned int)f2bf(li_) << 16) | f2bf(lr);
    }
}

// ---------------- K3: y = C2[4096][128] * Basis[128][8192], dbuf DMA pipeline ----------------
__global__ __launch_bounds__(256, 2) void idft_mfma(const short* __restrict__ C2h,
        const short* __restrict__ C2l, const short* __restrict__ T1h,
        const short* __restrict__ T1l, float* __restrict__ y) {
    __shared__ short ah[2][4096], al[2][4096];
    __shared__ short bh[2][4096], bl[2][4096];
    const int t = threadIdx.x;
    const int lane = t & 63, wid = t >> 6;
    const int wm = (wid >> 1) * 64, wn = (wid & 1) * 64;
    const int sb = blockIdx.x;                    // col block (s), 0..63
    const int rb = blockIdx.y;                    // row block, 0..31
    f4 acc[4][4];
    #pragma unroll
    for (int i = 0; i < 4; ++i)
        #pragma unroll
        for (int j = 0; j < 4; ++j) acc[i][j] = (f4){0.f, 0.f, 0.f, 0.f};

    #define DMA3(kc, buf)  {                                                       \
        const size_t ta = (size_t)(rb * 4 + (kc)) * 8192;                          \
        const size_t tb = (size_t)(sb * 4 + (kc)) * 8192;                          \
        const int wo = wid * 2048 + lane * 16;                                     \
        glds16((const char*)C2h + ta + wo,        (char*)&ah[buf][0] + wid * 2048);        \
        glds16((const char*)C2h + ta + wo + 1024, (char*)&ah[buf][0] + wid * 2048 + 1024); \
        glds16((const char*)C2l + ta + wo,        (char*)&al[buf][0] + wid * 2048);        \
        glds16((const char*)C2l + ta + wo + 1024, (char*)&al[buf][0] + wid * 2048 + 1024); \
        glds16((const char*)T1h + tb + wo,        (char*)&bh[buf][0] + wid * 2048);        \
        glds16((const char*)T1h + tb + wo + 1024, (char*)&bh[buf][0] + wid * 2048 + 1024); \
        glds16((const char*)T1l + tb + wo,        (char*)&bl[buf][0] + wid * 2048);        \
        glds16((const char*)T1l + tb + wo + 1024, (char*)&bl[buf][0] + wid * 2048 + 1024); }

    DMA3(0, 0);
    __syncthreads();
    #pragma unroll
    for (int kc = 0; kc < 4; ++kc) {
        const int cur = kc & 1;
        if (kc < 3) DMA3(kc + 1, cur ^ 1);
        {
            const int kk = (lane >> 4) * 8, rl = lane & 15;
            s8v Ah[4], Al[4], Bh[4], Bl[4];
            #pragma unroll
            for (int mf = 0; mf < 4; ++mf) {
                int us = SW32(wm + mf * 16 + rl, kk);
                Ah[mf] = *(const s8v*)&ah[cur][us];
                Al[mf] = *(const s8v*)&al[cur][us];
            }
            #pragma unroll
            for (int nf = 0; nf < 4; ++nf) {
                int us = SW32(wn + nf * 16 + rl, kk);
                Bh[nf] = *(const s8v*)&bh[cur][us];
                Bl[nf] = *(const s8v*)&bl[cur][us];
            }
            #pragma unroll
            for (int mf = 0; mf < 4; ++mf)
                #pragma unroll
                for (int nf = 0; nf < 4; ++nf)
                    acc[mf][nf] = __builtin_amdgcn_mfma_f32_16x16x32_bf16(Ah[mf], Bh[nf], acc[mf][nf], 0, 0, 0);
            #pragma unroll
            for (int mf = 0; mf < 4; ++mf)
                #pragma unroll
                for (int nf = 0; nf < 4; ++nf)
                    acc[mf][nf] = __builtin_amdgcn_mfma_f32_16x16x32_bf16(Al[mf], Bh[nf], acc[mf][nf], 0, 0, 0);
            #pragma unroll
            for (int mf = 0; mf < 4; ++mf)
                #pragma unroll
                for (int nf = 0; nf < 4; ++nf)
                    acc[mf][nf] = __builtin_amdgcn_mfma_f32_16x16x32_bf16(Ah[mf], Bl[nf], acc[mf][nf], 0, 0, 0);
        }
        __syncthreads();
    }
    #pragma unroll
    for (int mf = 0; mf < 4; ++mf) {
        int rr = rb * 128 + wm + mf * 16 + (lane >> 4) * 4;
        #pragma unroll
        for (int nf = 0; nf < 4; ++nf) {
            int c = sb * 128 + wn + nf * 16 + (lane & 15);
            #pragma unroll
            for (int r = 0; r < 4; ++r)
                __builtin_nontemporal_store(acc[mf][nf][r], &y[(size_t)(rr + r) * S_LEN + c]);
        }
    }
}

extern "C" void kernel_launch(void* const* d_in, const int* in_sizes, int n_in,
                              void* d_out, int out_size, void* d_ws, size_t ws_size,
                              hipStream_t stream) {
    const float* x      = (const float*)d_in[0];
    const float* w_real = (const float*)d_in[1];
    const float* w_imag = (const float*)d_in[2];
    float* y = (float*)d_out;

    const size_t TBL = (size_t)S_LEN * 128;       // 1M elems
    char* w0 = (char*)d_ws;
    short* T1h     = (short*)w0;                  // 2MB each half
    short* T1l     = T1h + TBL;
    _Float16* Bimg = (_Float16*)(T1l + TBL);      // 2MB
    float* X       = (float*)(Bimg + TBL);        // 2MB
    short* C2h     = (short*)(X + (size_t)4096 * 128);
    short* C2l     = C2h + (size_t)4096 * 128;
    float* P       = (float*)(C2l + (size_t)4096 * 128);   // 4MB (2 slices)
    float* tab     = P + 2 * (size_t)4096 * 128;           // 32KB
    float* Pdead   = tab + S_LEN;                          // 4MB (2 slices, dead)
    const size_t TOTAL = (size_t)((char*)(Pdead + 2 * (size_t)4096 * 128) - w0);  // ~20MB
    if (ws_size < TOTAL) {
        fprintf(stderr, "kernel_launch: ws too small (%zu < %zu bytes)\n", ws_size, TOTAL);
        return;
    }

    // ---- production pipeline ----
    gen_master<<<S_LEN / 256, 256, 0, stream>>>(tab);
    gen_t1_img<<<(S_LEN * 128) / 256, 256, 0, stream>>>(tab, T1h, T1l);
    gen_b_img<<<(S_LEN * 128) / 256, 256, 0, stream>>>(tab, Bimg);
    k1_t<1, false><<<dim3(4096 / 16, 2), 512, 0, stream>>>(x, Bimg, P);
    ksum<<<512, 256, 0, stream>>>(P, X);
    mode_contract<<<dim3(NM, 4), 256, 0, stream>>>(X, w_real, w_imag, C2h, C2l);
    idft_mfma<<<dim3(S_LEN / 128, 4096 / 128), 256, 0, stream>>>(C2h, C2l, T1h, T1l, y);

    // ---- diagnostics (dead outputs; displace poison-fills from rocprof top-5) ----
    kstream<<<dim3(4096 / 16, 2), 512, 0, stream>>>(x, y, Pdead);          // V1: A-pattern BW
    k1_t<10, true><<<dim3(4096 / 16, 2), 512, 0, stream>>>(x, Bimg, Pdead); // V2: machinery, no A
    k1_t<3, false><<<dim3(4096 / 16, 2), 512, 0, stream>>>(x, Bimg, Pdead); // V3: full, warm
}

// Round 10
// 123.339 us; speedup vs baseline: 3.9809x; 3.9809x over previous
//
#include <hip/hip_runtime.h>
#include <cstdio>

// B=32, Cin=128, S=8192, H=4, Hc=32, M=64, Cout=128
#define S_LEN 8192
#define NM 64

typedef short s8v __attribute__((ext_vector_type(8)));   // 8 bf16
typedef float f4  __attribute__((ext_vector_type(4)));
typedef _Float16 h8 __attribute__((ext_vector_type(8))); // 8 fp16 (MFMA f16 frag)

static __device__ inline unsigned short f2bf(float f) {  // RNE fp32->bf16
    unsigned int u = __builtin_bit_cast(unsigned int, f);
    u = (u + 0x7FFFu + ((u >> 16) & 1u)) >> 16;
    return (unsigned short)u;
}
static __device__ inline float bf2f(unsigned short h) {
    unsigned int u = ((unsigned int)h) << 16;
    return __builtin_bit_cast(float, u);
}

// K3-side swizzle: [128 r][32 k] tile, XOR k-bits 3..4 with (r>>1)&3
#define SW32(r, k) (((r) * 32) + ((k) ^ ((((r) >> 1) & 3) << 3)))

static __device__ __forceinline__ void glds16(const void* g, void* l) {
    __builtin_amdgcn_global_load_lds(
        (const __attribute__((address_space(1))) unsigned int*)g,
        (__attribute__((address_space(3))) unsigned int*)l, 16, 0, 0);
}

// ---------------- master trig table: tab[p] = cos(2*pi*p/8192) ----------------
__global__ __launch_bounds__(256) void gen_master(float* __restrict__ tab) {
    int p = blockIdx.x * 256 + threadIdx.x;
    tab[p] = cosf((float)p * (6.28318530717958647692f / (float)S_LEN));
}

// T1 image (K3's B^T): (s,k) k=2m|2m+1; img[(sb*4+kc)*4096 + SW32(s&127,k&31)]
// -sin(theta_p) == cos(theta_{p+2048})
__global__ __launch_bounds__(256) void gen_t1_img(const float* __restrict__ tab,
                                                  short* __restrict__ Th,
                                                  short* __restrict__ Tl) {
    int tid = blockIdx.x * 256 + threadIdx.x;     // 1M
    int tile = tid >> 12;
    int sb = tile >> 2, kc = tile & 3;
    int us = tid & 4095;
    int ls = us >> 5, kx = us & 31;
    int lk = kx ^ (((ls >> 1) & 3) << 3);
    int s = sb * 128 + ls;
    int k = kc * 32 + lk;
    int m = k >> 1;
    int p = (m * s + ((k & 1) << 11)) & (S_LEN - 1);
    float v = tab[p];                             // k odd -> -sin; k=1 gives 0 (Im(DC) dropped)
    unsigned short h = f2bf(v);
    Th[tid] = (short)h;
    Tl[tid] = (short)f2bf(v - bf2f(h));
}

// Bimg (K1's B LDS image): 128 tiles (k-steps of 64) x [128 c][64 k] fp16 = 16KB/tile.
// us(c,k) = c*64 + (((k>>3) ^ (c&7))<<3) + (k&7). val = (c&1) ? -sin(2pi m kg/S) : cos.
__global__ __launch_bounds__(256) void gen_b_img(const float* __restrict__ tab,
                                                 _Float16* __restrict__ Bimg) {
    int tid = blockIdx.x * 256 + threadIdx.x;     // 1M fp16
    int tk = tid >> 13;                           // tile 0..127
    int us = tid & 8191;
    int c = us >> 6;
    int wl = us & 63;
    int slot = wl >> 3, e = wl & 7;
    int k = ((slot ^ (c & 7)) << 3) | e;          // invert swizzle
    int kg = tk * 64 + k;
    int m = c >> 1;
    int p = (m * kg + ((c & 1) << 11)) & (S_LEN - 1);
    Bimg[tid] = (_Float16)tab[p];
}

// ---------------- K1: P[ks] = x * B1 ; BM=64 BN=128 BK=64, vm-free barriers ----------------
// 512 blocks (2/CU) x 512 thr (8 waves, 2M x 4N). 16 steps of BK=64 per block.
// A: fp32->fp16 hi/lo reg-staged dist-1; B: reg-staged dist-1 from pre-swizzled Bimg.
__global__ __launch_bounds__(512, 4) void dft_fwd_mfma(const float* __restrict__ x,
        const _Float16* __restrict__ Bimg, float* __restrict__ P) {
    __shared__ _Float16 abh[2][4096], abl[2][4096];   // A hi/lo [64r][64k], 8KB per buf
    __shared__ _Float16 bb[2][8192];                  // B [128c][64k], 16KB per buf
    const int t = threadIdx.x;
    const int lane = t & 63, w = t >> 6;
    const int rl = lane & 15, kq = lane >> 4;
    const int wr = w >> 2, wc = w & 3;                // 2M x 4N wave grid
    const int row0 = blockIdx.x * 64;
    const int ks = blockIdx.y;                        // 0..7 (K-chunk of 1024)
    // A staging: thread covers (row rA, 8 floats at slot sA)
    const int rA = t >> 3, sA = t & 7;
    const size_t xrow = (size_t)(row0 + rA) * S_LEN + (size_t)ks * 1024 + (size_t)sA * 8;
    const int usA = rA * 64 + ((sA ^ (rA & 7)) << 3);
    const size_t bby = (size_t)ks * 16 * 16384 + (size_t)t * 32;   // Bimg byte base (tile 0)

    f4 acc[2][2];
    #pragma unroll
    for (int i = 0; i < 2; ++i)
        #pragma unroll
        for (int j = 0; j < 2; ++j) acc[i][j] = (f4){0.f, 0.f, 0.f, 0.f};

    f4 aA0, aA1, aB0, aB1;
    h8 bA0, bA1, bB0, bB1;

    #define LA(SC, A0, A1) { A0 = *(const f4*)&x[xrow + (size_t)(SC) * 64];        \
                             A1 = *(const f4*)&x[xrow + (size_t)(SC) * 64 + 4]; }
    #define LB(SC, B0, B1) { const char* g = (const char*)Bimg + bby +             \
                                 (size_t)(SC) * 16384;                             \
                             B0 = *(const h8*)g; B1 = *(const h8*)(g + 16); }
    #define CV(A0, A1, NXT) { h8 hv, lv;                                           \
        _Pragma("unroll")                                                          \
        for (int e = 0; e < 4; ++e) {                                              \
            float f = A0[e]; _Float16 hh = (_Float16)f;                            \
            hv[e] = hh; lv[e] = (_Float16)(f - (float)hh);                         \
        }                                                                          \
        _Pragma("unroll")                                                          \
        for (int e = 0; e < 4; ++e) {                                              \
            float f = A1[e]; _Float16 hh = (_Float16)f;                            \
            hv[4 + e] = hh; lv[4 + e] = (_Float16)(f - (float)hh);                 \
        }                                                                          \
        *(h8*)&abh[NXT][usA] = hv;                                                 \
        *(h8*)&abl[NXT][usA] = lv; }
    #define WB(B0, B1, NXT) { *(h8*)&bb[NXT][t * 16] = B0;                         \
                              *(h8*)&bb[NXT][t * 16 + 8] = B1; }
    #define MM(CUR) { _Pragma("unroll")                                            \
        for (int ksl = 0; ksl < 2; ++ksl) {                                        \
            const int sb_ = ksl * 4 + kq;                                          \
            h8 Ah0, Al0, Ah1, Al1, Bv0, Bv1;                                       \
            { int r = wr * 32 + rl;      int u = r * 64 + ((sb_ ^ (r & 7)) << 3);  \
              Ah0 = *(const h8*)&abh[CUR][u]; Al0 = *(const h8*)&abl[CUR][u]; }    \
            { int r = wr * 32 + 16 + rl; int u = r * 64 + ((sb_ ^ (r & 7)) << 3);  \
              Ah1 = *(const h8*)&abh[CUR][u]; Al1 = *(const h8*)&abl[CUR][u]; }    \
            { int c = wc * 32 + rl;      int u = c * 64 + ((sb_ ^ (c & 7)) << 3);  \
              Bv0 = *(const h8*)&bb[CUR][u]; }                                     \
            { int c = wc * 32 + 16 + rl; int u = c * 64 + ((sb_ ^ (c & 7)) << 3);  \
              Bv1 = *(const h8*)&bb[CUR][u]; }                                     \
            acc[0][0] = __builtin_amdgcn_mfma_f32_16x16x32_f16(Ah0, Bv0, acc[0][0], 0, 0, 0); \
            acc[0][1] = __builtin_amdgcn_mfma_f32_16x16x32_f16(Ah0, Bv1, acc[0][1], 0, 0, 0); \
            acc[1][0] = __builtin_amdgcn_mfma_f32_16x16x32_f16(Ah1, Bv0, acc[1][0], 0, 0, 0); \
            acc[1][1] = __builtin_amdgcn_mfma_f32_16x16x32_f16(Ah1, Bv1, acc[1][1], 0, 0, 0); \
            acc[0][0] = __builtin_amdgcn_mfma_f32_16x16x32_f16(Al0, Bv0, acc[0][0], 0, 0, 0); \
            acc[0][1] = __builtin_amdgcn_mfma_f32_16x16x32_f16(Al0, Bv1, acc[0][1], 0, 0, 0); \
            acc[1][0] = __builtin_amdgcn_mfma_f32_16x16x32_f16(Al1, Bv0, acc[1][0], 0, 0, 0); \
            acc[1][1] = __builtin_amdgcn_mfma_f32_16x16x32_f16(Al1, Bv1, acc[1][1], 0, 0, 0); \
        } }
    #define BAR  __builtin_amdgcn_sched_barrier(0);                                \
        asm volatile("s_waitcnt lgkmcnt(0)" ::: "memory");                         \
        __builtin_amdgcn_sched_barrier(0);                                         \
        __builtin_amdgcn_s_barrier();                                              \
        __builtin_amdgcn_sched_barrier(0);

    // prologue: A(0),A(1),B(0),B(1) in flight; stage step 0 into buf0
    LA(0, aA0, aA1) LA(1, aB0, aB1) LB(0, bA0, bA1) LB(1, bB0, bB1)
    __builtin_amdgcn_sched_barrier(0);
    CV(aA0, aA1, 0) WB(bA0, bA1, 0)
    BAR
    for (int s = 0; s < 14; s += 2) {
        // even step: CUR=0, NXT=1
        LA(s + 2, aA0, aA1) LB(s + 2, bA0, bA1)
        __builtin_amdgcn_sched_barrier(0);
        CV(aB0, aB1, 1) WB(bB0, bB1, 1)
        MM(0)
        BAR
        // odd step: CUR=1, NXT=0
        LA(s + 3, aB0, aB1) LB(s + 3, bB0, bB1)
        __builtin_amdgcn_sched_barrier(0);
        CV(aA0, aA1, 0) WB(bA0, bA1, 0)
        MM(1)
        BAR
    }
    // step 14 (even): loads clamped to 15 (dup, never consumed)
    LA(15, aA0, aA1) LB(15, bA0, bA1)
    __builtin_amdgcn_sched_barrier(0);
    CV(aB0, aB1, 1) WB(bB0, bB1, 1)
    MM(0)
    BAR
    // step 15: MFMA only
    MM(1)

    // D layout: col=lane&15, row=(lane>>4)*4+reg
    float* Pks = P + (size_t)ks * 524288;
    #pragma unroll
    for (int mf = 0; mf < 2; ++mf)
        #pragma unroll
        for (int nf = 0; nf < 2; ++nf)
            #pragma unroll
            for (int r = 0; r < 4; ++r)
                Pks[(size_t)(row0 + wr * 32 + mf * 16 + kq * 4 + r) * 128
                    + wc * 32 + nf * 16 + rl] = acc[mf][nf][r];
}

// ---------------- ksum: X = sum of 8 P slices ----------------
__global__ __launch_bounds__(256) void ksum(const float* __restrict__ P,
                                            float* __restrict__ X) {
    int i = (blockIdx.x * 256 + threadIdx.x) * 4;
    f4 s = (f4){0.f, 0.f, 0.f, 0.f};
    #pragma unroll
    for (int ks = 0; ks < 8; ++ks)
        s += *(const f4*)&P[(size_t)ks * 524288 + i];
    *(f4*)&X[i] = s;
}

// ---------------- K2: mode contraction -> C2 image (pre-swizzled bf16 hi/lo) ----------------
__global__ __launch_bounds__(256) void mode_contract(const float* __restrict__ X,
        const float* __restrict__ w_real, const float* __restrict__ w_imag,
        short* __restrict__ C2h, short* __restrict__ C2l) {
    __shared__ float xr[32][128], xi[32][128];
    __shared__ float wr[128][32], wi[128][32];
    const int m = blockIdx.x, h = blockIdx.y, t = threadIdx.x;
    #pragma unroll
    for (int it = 0; it < 16; ++it) {
        int li = t + it * 256;       // 0..4095
        int b = li >> 7, i = li & 127;
        const float2 v = *(const float2*)&X[(size_t)(b * 128 + i) * 128 + 2 * m];
        xr[b][i] = v.x; xi[b][i] = v.y;
        int i2 = li >> 5, o = li & 31;
        size_t off = ((size_t)((h * 128 + i2) * 32 + o)) * NM + m;
        wr[i2][o] = w_real[off];
        wi[i2][o] = w_imag[off];
    }
    __syncthreads();
    const int o = t & 31;
    const int b0 = (t >> 5) * 4;
    float re[4] = {0.f, 0.f, 0.f, 0.f}, im[4] = {0.f, 0.f, 0.f, 0.f};
    for (int i = 0; i < 128; ++i) {
        float wrv = wr[i][o], wiv = wi[i][o];
        #pragma unroll
        for (int j = 0; j < 4; ++j) {
            float a = xr[b0 + j][i], c = xi[b0 + j][i];
            re[j] += a * wrv - c * wiv;
            im[j] += a * wiv + c * wrv;
        }
    }
    const float alpha = (m == 0) ? (1.0f / (float)S_LEN) : (2.0f / (float)S_LEN);
    const int kc = m >> 4;
    const int lk = (2 * m) & 31;
    #pragma unroll
    for (int j = 0; j < 4; ++j) {
        int row = (b0 + j) * 128 + h * 32 + o;
        float vr = alpha * re[j], vi = alpha * im[j];
        unsigned short hr = f2bf(vr), hi_ = f2bf(vi);
        float lr = vr - bf2f(hr), li_ = vi - bf2f(hi_);
        int rb = row >> 7, lr_ = row & 127;
        size_t ui = ((size_t)(rb * 4 + kc) * 4096 + SW32(lr_, lk)) >> 1;   // uint index
        ((unsigned int*)C2h)[ui] = ((unsigned int)hi_ << 16) | hr;
        ((unsigned int*)C2l)[ui] = ((unsigned int)f2bf(li_) << 16) | f2bf(lr);
    }
}

// ---------------- K3: y = C2[4096][128] * Basis[128][8192], dbuf DMA pipeline ----------------
__global__ __launch_bounds__(256, 2) void idft_mfma(const short* __restrict__ C2h,
        const short* __restrict__ C2l, const short* __restrict__ T1h,
        const short* __restrict__ T1l, float* __restrict__ y) {
    __shared__ short ah[2][4096], al[2][4096];
    __shared__ short bh[2][4096], bl[2][4096];
    const int t = threadIdx.x;
    const int lane = t & 63, wid = t >> 6;
    const int wm = (wid >> 1) * 64, wn = (wid & 1) * 64;
    const int sb = blockIdx.x;                    // col block (s), 0..63
    const int rb = blockIdx.y;                    // row block, 0..31
    f4 acc[4][4];
    #pragma unroll
    for (int i = 0; i < 4; ++i)
        #pragma unroll
        for (int j = 0; j < 4; ++j) acc[i][j] = (f4){0.f, 0.f, 0.f, 0.f};

    #define DMA3(kc, buf)  {                                                       \
        const size_t ta = (size_t)(rb * 4 + (kc)) * 8192;                          \
        const size_t tb = (size_t)(sb * 4 + (kc)) * 8192;                          \
        const int wo = wid * 2048 + lane * 16;                                     \
        glds16((const char*)C2h + ta + wo,        (char*)&ah[buf][0] + wid * 2048);        \
        glds16((const char*)C2h + ta + wo + 1024, (char*)&ah[buf][0] + wid * 2048 + 1024); \
        glds16((const char*)C2l + ta + wo,        (char*)&al[buf][0] + wid * 2048);        \
        glds16((const char*)C2l + ta + wo + 1024, (char*)&al[buf][0] + wid * 2048 + 1024); \
        glds16((const char*)T1h + tb + wo,        (char*)&bh[buf][0] + wid * 2048);        \
        glds16((const char*)T1h + tb + wo + 1024, (char*)&bh[buf][0] + wid * 2048 + 1024); \
        glds16((const char*)T1l + tb + wo,        (char*)&bl[buf][0] + wid * 2048);        \
        glds16((const char*)T1l + tb + wo + 1024, (char*)&bl[buf][0] + wid * 2048 + 1024); }

    DMA3(0, 0);
    __syncthreads();
    #pragma unroll
    for (int kc = 0; kc < 4; ++kc) {
        const int cur = kc & 1;
        if (kc < 3) DMA3(kc + 1, cur ^ 1);
        {
            const int kk = (lane >> 4) * 8, rl = lane & 15;
            s8v Ah[4], Al[4], Bh[4], Bl[4];
            #pragma unroll
            for (int mf = 0; mf < 4; ++mf) {
                int us = SW32(wm + mf * 16 + rl, kk);
                Ah[mf] = *(const s8v*)&ah[cur][us];
                Al[mf] = *(const s8v*)&al[cur][us];
            }
            #pragma unroll
            for (int nf = 0; nf < 4; ++nf) {
                int us = SW32(wn + nf * 16 + rl, kk);
                Bh[nf] = *(const s8v*)&bh[cur][us];
                Bl[nf] = *(const s8v*)&bl[cur][us];
            }
            #pragma unroll
            for (int mf = 0; mf < 4; ++mf)
                #pragma unroll
                for (int nf = 0; nf < 4; ++nf)
                    acc[mf][nf] = __builtin_amdgcn_mfma_f32_16x16x32_bf16(Ah[mf], Bh[nf], acc[mf][nf], 0, 0, 0);
            #pragma unroll
            for (int mf = 0; mf < 4; ++mf)
                #pragma unroll
                for (int nf = 0; nf < 4; ++nf)
                    acc[mf][nf] = __builtin_amdgcn_mfma_f32_16x16x32_bf16(Al[mf], Bh[nf], acc[mf][nf], 0, 0, 0);
            #pragma unroll
            for (int mf = 0; mf < 4; ++mf)
                #pragma unroll
                for (int nf = 0; nf < 4; ++nf)
                    acc[mf][nf] = __builtin_amdgcn_mfma_f32_16x16x32_bf16(Ah[mf], Bl[nf], acc[mf][nf], 0, 0, 0);
        }
        __syncthreads();
    }
    #pragma unroll
    for (int mf = 0; mf < 4; ++mf) {
        int rr = rb * 128 + wm + mf * 16 + (lane >> 4) * 4;
        #pragma unroll
        for (int nf = 0; nf < 4; ++nf) {
            int c = sb * 128 + wn + nf * 16 + (lane & 15);
            #pragma unroll
            for (int r = 0; r < 4; ++r)
                __builtin_nontemporal_store(acc[mf][nf][r], &y[(size_t)(rr + r) * S_LEN + c]);
        }
    }
}

extern "C" void kernel_launch(void* const* d_in, const int* in_sizes, int n_in,
                              void* d_out, int out_size, void* d_ws, size_t ws_size,
                              hipStream_t stream) {
    const float* x      = (const float*)d_in[0];
    const float* w_real = (const float*)d_in[1];
    const float* w_imag = (const float*)d_in[2];
    float* y = (float*)d_out;

    const size_t TBL = (size_t)S_LEN * 128;       // 1M elems
    char* w0 = (char*)d_ws;
    short* T1h     = (short*)w0;                  // 2MB each half
    short* T1l     = T1h + TBL;
    _Float16* Bimg = (_Float16*)(T1l + TBL);      // 2MB, K1 LDS-tile image
    float* X       = (float*)(Bimg + TBL);        // 2MB
    float* tab     = X + (size_t)4096 * 128;      // 32KB
    float* P       = tab + S_LEN;                 // 16MB (8 slices)
    // C2 overlaps P (disjoint lifetimes: P dead after ksum; C2 born at K2)
    short* C2h     = (short*)P;
    short* C2l     = C2h + TBL;
    const size_t TOTAL = (size_t)((char*)(P + 8 * (size_t)4096 * 128) - w0);  // ~24MB
    if (ws_size < TOTAL) {
        fprintf(stderr, "kernel_launch: ws too small (%zu < %zu bytes)\n", ws_size, TOTAL);
        return;
    }

    gen_master<<<S_LEN / 256, 256, 0, stream>>>(tab);
    gen_t1_img<<<(S_LEN * 128) / 256, 256, 0, stream>>>(tab, T1h, T1l);
    gen_b_img<<<(S_LEN * 128) / 256, 256, 0, stream>>>(tab, Bimg);
    dft_fwd_mfma<<<dim3(64, 8), 512, 0, stream>>>(x, Bimg, P);
    ksum<<<512, 256, 0, stream>>>(P, X);
    mode_contract<<<dim3(NM, 4), 256, 0, stream>>>(X, w_real, w_imag, C2h, C2l);
    idft_mfma<<<dim3(S_LEN / 128, 4096 / 128), 256, 0, stream>>>(C2h, C2l, T1h, T1l, y);
}